// Round 9
// baseline (270.704 us; speedup 1.0000x reference)
//
#include <hip/hip_runtime.h>

#define S_LEN 4096
#define DIM   1024
#define NH    16
#define HD    64

typedef __bf16 bf16;
typedef __attribute__((ext_vector_type(8)))  __bf16 bf16x8;
typedef __attribute__((ext_vector_type(4)))  float  f32x4;
typedef __attribute__((ext_vector_type(16))) float  f32x16;
typedef __attribute__((ext_vector_type(4)))  unsigned int uint4v;

typedef __attribute__((address_space(3))) void lds_void;
typedef __attribute__((address_space(1))) void g_void;

#if __has_builtin(__builtin_amdgcn_exp2f)
#define EXP2(x) __builtin_amdgcn_exp2f(x)
#else
#define EXP2(x) exp2f(x)
#endif

// async global->LDS, 16B per lane. LDS dest = wave-uniform base + lane*16.
__device__ __forceinline__ void gl_lds16(const void* g, void* l) {
    __builtin_amdgcn_global_load_lds((g_void*)(void*)g, (lds_void*)l, 16, 0, 0);
}

// pack 2 floats -> 2 bf16 in a dword (v_cvt_pk_bf16_f32)
__device__ __forceinline__ unsigned int pk2(float a, float b) {
    unsigned short ua = __builtin_bit_cast(unsigned short, (bf16)a);
    unsigned short ub = __builtin_bit_cast(unsigned short, (bf16)b);
    return (unsigned int)ua | ((unsigned int)ub << 16);
}

// key-axis permutation for V^T: swap bits 2<->3 (involution, closed within
// each 16-slot MFMA group). Makes PV's A-fragment lane-local (no shuffles).
__device__ __forceinline__ int ksw23(int x) {
    return (x & ~12) | ((x & 8) >> 1) | ((x & 4) << 1);
}

// ---------------- fused fp32 -> bf16 conversions (1 launch, G13) ----------
// grid 4096: [0,2048) x -> xb; [2048,2560) wq; [2560,3072) wk;
// [3072,3584) wv (into wqkv slabs); [3584,4096) wo -> wob.
__global__ __launch_bounds__(256) void f2b_all(
    const float* __restrict__ x,  const float* __restrict__ wq,
    const float* __restrict__ wk, const float* __restrict__ wv,
    const float* __restrict__ wo,
    bf16* __restrict__ xb, bf16* __restrict__ wqkv, bf16* __restrict__ wob)
{
    int b = blockIdx.x;
    const float* src; bf16* dst; int base;
    if (b < 2048)      { src = x;  dst = xb;              base = b; }
    else if (b < 2560) { src = wq; dst = wqkv;            base = b - 2048; }
    else if (b < 3072) { src = wk; dst = wqkv + 1048576;  base = b - 2560; }
    else if (b < 3584) { src = wv; dst = wqkv + 2097152;  base = b - 3072; }
    else               { src = wo; dst = wob;             base = b - 3584; }
    int i = base * 2048 + threadIdx.x * 8;
    float4 a = *(const float4*)(src + i);
    float4 c = *(const float4*)(src + i + 4);
    bf16x8 r;
    r[0]=(bf16)a.x; r[1]=(bf16)a.y; r[2]=(bf16)a.z; r[3]=(bf16)a.w;
    r[4]=(bf16)c.x; r[5]=(bf16)c.y; r[6]=(bf16)c.z; r[7]=(bf16)c.w;
    *(bf16x8*)(dst + i) = r;
}

// ---------------- m97-style GEMM: C = A * B^T (A[M][K], B[N][K]) ----------
// MODE 0: fp32 out [M][N].
// MODE 1: QKV: cols [0,1024)->outQ[s][c], [1024,2048)->outK[s][c] (bf16);
//   [2048,3072)->V^T directly: outV = vt[H][64][S_LEN], stored with the
//   per-64-key-tile bit2<->3 permutation and (d&7)<<3 XOR pre-swizzle.
template <int MODE>
__global__ __launch_bounds__(256) void gemm_bt(
    const bf16* __restrict__ A, const bf16* __restrict__ B,
    int M, int N, int K,
    float* __restrict__ outF,
    bf16* __restrict__ outQ, bf16* __restrict__ outK, bf16* __restrict__ outV)
{
    __shared__ bf16 As[128][32];
    __shared__ bf16 Bs[128][32];
    const int bm = blockIdx.x, bn = blockIdx.y;
    const int tid  = threadIdx.x;
    const int wave = tid >> 6, lane = tid & 63;
    const int g = lane >> 4, r = lane & 15;
    const int wr = wave >> 1, wc = wave & 1;
    const int rr = lane >> 2, cc = (lane & 3) * 8;

    f32x4 acc[4][4] = {};

    const bf16* Ab = A + (size_t)(bm * 128) * K;
    const bf16* Bb = B + (size_t)(bn * 128) * K;

    for (int k0 = 0; k0 < K; k0 += 32) {
        #pragma unroll
        for (int i = 0; i < 2; ++i) {
            gl_lds16(Ab + (size_t)(wave*32 + i*16 + rr) * K + k0 + cc, &As[wave*32 + i*16][0]);
            gl_lds16(Bb + (size_t)(wave*32 + i*16 + rr) * K + k0 + cc, &Bs[wave*32 + i*16][0]);
        }
        __syncthreads();
        bf16x8 a[4], b[4];
        #pragma unroll
        for (int m = 0; m < 4; ++m) a[m] = *(const bf16x8*)&As[wr*64 + m*16 + r][g*8];
        #pragma unroll
        for (int n = 0; n < 4; ++n) b[n] = *(const bf16x8*)&Bs[wc*64 + n*16 + r][g*8];
        #pragma unroll
        for (int m = 0; m < 4; ++m)
            #pragma unroll
            for (int n = 0; n < 4; ++n)
                acc[m][n] = __builtin_amdgcn_mfma_f32_16x16x32_bf16(a[m], b[n], acc[m][n], 0, 0, 0);
        __syncthreads();
    }

    #pragma unroll
    for (int m = 0; m < 4; ++m)
        #pragma unroll
        for (int n = 0; n < 4; ++n)
            #pragma unroll
            for (int i = 0; i < 4; ++i) {
                int row = bm*128 + wr*64 + m*16 + g*4 + i;
                int col = bn*128 + wc*64 + n*16 + r;
                float val = acc[m][n][i];
                if (MODE == 0) {
                    outF[(size_t)row * N + col] = val;
                } else {
                    if (col < 1024)       outQ[(size_t)row * 1024 + col]          = (bf16)val;
                    else if (col < 2048)  outK[(size_t)row * 1024 + (col - 1024)] = (bf16)val;
                    else {
                        int c = col - 2048;
                        int hh = c >> 6, d = c & 63;
                        int pos = ksw23(row & 63) ^ ((d & 7) << 3);
                        outV[((size_t)(hh * HD + d)) * S_LEN + (row & ~63) + pos] = (bf16)val;
                    }
                }
            }
}

// ---------------- per-head RMSNorm + RoPE, [S][1024] -> [H][S][64] --------
// 8 rows per wave, bf16x8 vectorized (G13). Group reduce: shfl_xor 1,2,4.
// RoPE partner (d +/- 32) = shfl_xor(.,4). K pre-swizzled: d ^ ((s&7)<<3).
__global__ __launch_bounds__(256) void norm_rope(
    const bf16* __restrict__ qr, const bf16* __restrict__ kr,
    const float* __restrict__ cosb, const float* __restrict__ sinb,
    const float* __restrict__ qw, const float* __restrict__ kw,
    bf16* __restrict__ qo, bf16* __restrict__ ko)
{
    int wgl  = blockIdx.x * 4 + (threadIdx.x >> 6);   // [0, 16384)
    int lane = threadIdx.x & 63;
    int isK  = wgl >= 8192;
    int w2   = wgl & 8191;
    int s    = w2 >> 1;
    int h    = ((w2 & 1) << 3) + (lane >> 3);
    int d0   = (lane & 7) << 3;
    const bf16*  src = isK ? kr : qr;
    const float* w   = isK ? kw : qw;

    bf16x8 xv = *(const bf16x8*)(src + (size_t)s * DIM + h * HD + d0);
    float x[8];
    #pragma unroll
    for (int e = 0; e < 8; ++e) x[e] = (float)xv[e];
    float ss = 0.f;
    #pragma unroll
    for (int e = 0; e < 8; ++e) ss += x[e] * x[e];
    ss += __shfl_xor(ss, 1);
    ss += __shfl_xor(ss, 2);
    ss += __shfl_xor(ss, 4);
    float rn = rsqrtf(ss * (1.0f / 64.0f) + 1e-6f);

    float4 w0 = *(const float4*)(w + d0);
    float4 w1 = *(const float4*)(w + d0 + 4);
    float wv[8] = {w0.x, w0.y, w0.z, w0.w, w1.x, w1.y, w1.z, w1.w};
    float xn[8], pr[8];
    #pragma unroll
    for (int e = 0; e < 8; ++e) xn[e] = x[e] * rn * wv[e];
    #pragma unroll
    for (int e = 0; e < 8; ++e) pr[e] = __shfl_xor(xn[e], 4);

    int dm = d0 & 31;
    float4 c0 = *(const float4*)(cosb + s * 32 + dm);
    float4 c1 = *(const float4*)(cosb + s * 32 + dm + 4);
    float4 sn0 = *(const float4*)(sinb + s * 32 + dm);
    float4 sn1 = *(const float4*)(sinb + s * 32 + dm + 4);
    float cv[8] = {c0.x, c0.y, c0.z, c0.w, c1.x, c1.y, c1.z, c1.w};
    float sv[8] = {sn0.x, sn0.y, sn0.z, sn0.w, sn1.x, sn1.y, sn1.z, sn1.w};

    const bool lo = (d0 < 32);
    bf16x8 y;
    #pragma unroll
    for (int e = 0; e < 8; ++e) {
        float t = lo ? (xn[e] * cv[e] - pr[e] * sv[e])
                     : (xn[e] * cv[e] + pr[e] * sv[e]);
        y[e] = (bf16)t;
    }
    size_t ob = ((size_t)h * S_LEN + s) * HD;
    if (isK) *(bf16x8*)(ko + ob + (d0 ^ ((s & 7) << 3))) = y;
    else     *(bf16x8*)(qo + ob + d0)                    = y;
}

// ---------------- causal flash attention, 32x32 MFMA, 4-chunk split -------
// 2048 blocks = queue at 4/CU. idx: h = idx&15; u = idx>>4: qt = 31-(u>>2)
// (LPT order), c = u&3; tiles t in [c*nt/4, (c+1)*nt/4), nt = 2qt+2.
// Static-max softmax (diag score = +8 exactly): P = exp2(S*C1 - C2) -- pure
// sums, chunk partials (bf16 O slabs + fp32 l) combine by addition.
// Swapped QK^T: lane q = lane&31 owns its q-row's P at
// k = kn*32 + (rg&3) + 8*(rg>>2) + 4*hi (verified 32x32 C/D layout).
// V^T pre-permuted (ksw23) + XOR-swizzled -> PV A-fragment is lane-local.
// VALU diet (r8 post-mortem: VALU-throughput-bound at 68% busy): unroll-2
// with compile-time buffer index (hoists all LDS fragment addresses),
// incremental staging pointers, 4-chain tree sum.
__global__ __launch_bounds__(256, 4) void attn_kernel(
    const bf16* __restrict__ q, const bf16* __restrict__ k,
    const bf16* __restrict__ vt,
    bf16* __restrict__ Opc, float* __restrict__ lpc)
{
    __shared__ bf16 Ks[2][64][64];   // [keys][d], rows pre-swizzled
    __shared__ bf16 Vt[2][64][64];   // [d][keys], permuted+pre-swizzled

    const int idx = blockIdx.x;
    const int h = idx & 15;
    const int u = idx >> 4;
    const int qt = 31 - (u >> 2);
    const int c  = u & 3;
    const int nt = 2 * qt + 2;
    const int t0 = (c * nt) >> 2;
    const int t1 = ((c + 1) * nt) >> 2;

    const int q0 = qt * 128;
    const int tid = threadIdx.x;
    const int wave = tid >> 6, lane = tid & 63;
    const int l31 = lane & 31, hi = lane >> 5;

    const bf16* qh  = q  + (size_t)h * S_LEN * HD;
    const bf16* kh  = k  + (size_t)h * S_LEN * HD;
    const bf16* vth = vt + (size_t)h * HD * S_LEN;

    // Q B-fragments: lane holds its q-row (q0+wave*32+l31), 8 d-elems per step
    const int qrow = q0 + wave * 32 + l31;
    bf16x8 qf[4];
    #pragma unroll
    for (int ds4 = 0; ds4 < 4; ++ds4)
        qf[ds4] = *(const bf16x8*)(qh + (size_t)qrow * HD + ds4 * 16 + hi * 8);

    float l_run = 0.f;
    f32x16 acc_o[2] = {};

    const int srow = lane >> 3, scol = (lane & 7) * 8;
    const float C1 = 0.125f * 1.44269504088896f;   // scale * log2(e)
    const float C2 = 8.0f * 1.44269504088896f;     // static max * log2(e)

    // incremental staging pointers (advance per staged tile; no k0 rebuild)
    const bf16* kptr = kh  + (size_t)(t0 * 64 + wave * 16) * HD;
    const bf16* vptr = vth + (size_t)(wave * 16) * S_LEN + t0 * 64;

    auto stage = [&](int buf) {
        gl_lds16(kptr + (size_t)(srow    ) * HD + scol,    &Ks[buf][wave * 16][0]);
        gl_lds16(kptr + (size_t)(srow + 8) * HD + scol,    &Ks[buf][wave * 16 + 8][0]);
        gl_lds16(vptr + (size_t)(srow    ) * S_LEN + scol, &Vt[buf][wave * 16][0]);
        gl_lds16(vptr + (size_t)(srow + 8) * S_LEN + scol, &Vt[buf][wave * 16 + 8][0]);
        kptr += 64 * HD;
        vptr += 64;
    };

    auto compute = [&](int t, const bf16 (*Ksb)[64], const bf16 (*Vtb)[64]) {
        const int k0 = t * 64;
        const bool masked = (t >= 2 * qt);

        // S^T = K Q^T: A = K-rows (row = l31), B = Q (col = l31)
        f32x16 sacc[2];
        __builtin_amdgcn_s_setprio(1);
        #pragma unroll
        for (int kn = 0; kn < 2; ++kn) {
            const int krow = kn * 32 + l31;
            const int sw = (krow & 7) << 3;
            f32x16 z = {};
            #pragma unroll
            for (int ds4 = 0; ds4 < 4; ++ds4) {
                bf16x8 kfr = *(const bf16x8*)&Ksb[krow][(ds4 * 16 + hi * 8) ^ sw];
                z = __builtin_amdgcn_mfma_f32_32x32x16_bf16(kfr, qf[ds4], z, 0, 0, 0);
            }
            sacc[kn] = z;
        }
        __builtin_amdgcn_s_setprio(0);

        // static-max softmax, fully in-register; lane owns q-row qrow
        float p[32];
        #pragma unroll
        for (int kn = 0; kn < 2; ++kn)
            #pragma unroll
            for (int rg = 0; rg < 16; ++rg) {
                float e = EXP2(fmaf(sacc[kn][rg], C1, -C2));
                if (masked) {
                    int kloc = kn * 32 + (rg & 3) + 8 * (rg >> 2) + 4 * hi;
                    if (k0 + kloc > qrow) e = 0.f;
                }
                p[kn * 16 + rg] = e;
            }
        // tree sum: 4 independent chains of 8
        float s0 = 0.f, s1 = 0.f, s2 = 0.f, s3 = 0.f;
        #pragma unroll
        for (int j = 0; j < 8; ++j) {
            s0 += p[4*j];   s1 += p[4*j+1];
            s2 += p[4*j+2]; s3 += p[4*j+3];
        }
        float rs = (s0 + s1) + (s2 + s3);
        rs += __shfl_xor(rs, 32);
        l_run += rs;

        // P -> A-fragments: lane-local thanks to V^T key permutation.
        bf16x8 pa[4];
        #pragma unroll
        for (int ks4 = 0; ks4 < 4; ++ks4) {
            uint4v w;
            w.x = pk2(p[8*ks4+0], p[8*ks4+1]);
            w.y = pk2(p[8*ks4+2], p[8*ks4+3]);
            w.z = pk2(p[8*ks4+4], p[8*ks4+5]);
            w.w = pk2(p[8*ks4+6], p[8*ks4+7]);
            pa[ks4] = __builtin_bit_cast(bf16x8, w);
        }

        // O += P V: A = P (row = l31 = own q-row), B = V^T (col d = l31)
        __builtin_amdgcn_s_setprio(1);
        #pragma unroll
        for (int n = 0; n < 2; ++n) {
            const int d = n * 32 + l31;
            const int sw = (d & 7) << 3;
            f32x16 a = acc_o[n];
            #pragma unroll
            for (int ks4 = 0; ks4 < 4; ++ks4) {
                bf16x8 vfr = *(const bf16x8*)&Vtb[d][(ks4 * 16 + hi * 8) ^ sw];
                a = __builtin_amdgcn_mfma_f32_32x32x16_bf16(pa[ks4], vfr, a, 0, 0, 0);
            }
            acc_o[n] = a;
        }
        __builtin_amdgcn_s_setprio(0);
    };

    if (t0 < t1) {
        stage(0);
        asm volatile("s_waitcnt vmcnt(0)" ::: "memory");
        __syncthreads();
        const int n = t1 - t0;
        int i = 0;
        for (; i + 2 <= n; i += 2) {
            stage(1);                             // tile t0+i+1 -> buf1
            compute(t0 + i, Ks[0], Vt[0]);
            asm volatile("s_waitcnt vmcnt(0)" ::: "memory");
            __syncthreads();
            if (i + 2 < n) stage(0);              // tile t0+i+2 -> buf0
            compute(t0 + i + 1, Ks[1], Vt[1]);
            asm volatile("s_waitcnt vmcnt(0)" ::: "memory");
            __syncthreads();
        }
        if (i < n) compute(t0 + i, Ks[0], Vt[0]); // odd tail (already staged)
    }

    // partial epilogue: bf16 O slab for this chunk + fp32 l. C/D: col = l31,
    // row q = (rg&3) + 8*(rg>>2) + 4*hi. Empty chunks write zeros.
    bf16* Op = Opc + (size_t)c * S_LEN * DIM;
    #pragma unroll
    for (int n = 0; n < 2; ++n)
        #pragma unroll
        for (int rg = 0; rg < 16; ++rg) {
            int s_abs = q0 + wave * 32 + (rg & 3) + 8 * (rg >> 2) + 4 * hi;
            Op[(size_t)s_abs * DIM + h * HD + n * 32 + l31] = (bf16)acc_o[n][rg];
        }
    if (lane < 32)
        lpc[c * (NH * S_LEN) + h * S_LEN + (q0 + wave * 32 + lane)] = l_run;
}

// ---------------- combine 4 chunk partials + normalize -> bf16 ------------
__global__ __launch_bounds__(256) void combine_kernel(
    const bf16* __restrict__ Opc, const float* __restrict__ lpc,
    bf16* __restrict__ o)
{
    int gid = blockIdx.x * 256 + threadIdx.x;
    int e = gid * 8;
    int s = e >> 10, h = (e & 1023) >> 6;
    float a[8] = {};
    #pragma unroll
    for (int c = 0; c < 4; ++c) {
        bf16x8 v = *(const bf16x8*)(Opc + (size_t)c * S_LEN * DIM + e);
        #pragma unroll
        for (int j = 0; j < 8; ++j) a[j] += (float)v[j];
    }
    float l = 0.f;
    #pragma unroll
    for (int c = 0; c < 4; ++c) l += lpc[c * (NH * S_LEN) + h * S_LEN + s];
    float inv = __builtin_amdgcn_rcpf(l);
    bf16x8 rv;
    #pragma unroll
    for (int j = 0; j < 8; ++j) rv[j] = (bf16)(a[j] * inv);
    *(bf16x8*)(o + e) = rv;
}

// ---------------------------------------------------------------------------
extern "C" void kernel_launch(void* const* d_in, const int* in_sizes, int n_in,
                              void* d_out, int out_size, void* d_ws, size_t ws_size,
                              hipStream_t stream)
{
    const float* x    = (const float*)d_in[0];
    const float* cosb = (const float*)d_in[1];
    const float* sinb = (const float*)d_in[2];
    const float* wq   = (const float*)d_in[4];
    const float* wk   = (const float*)d_in[5];
    const float* wv   = (const float*)d_in[6];
    const float* wo   = (const float*)d_in[7];
    const float* qw   = (const float*)d_in[8];
    const float* kw   = (const float*)d_in[9];

    char* ws = (char*)d_ws;
    const size_t MB = 1024 * 1024;
    // region map (MB), temporal reuse:
    // [0,2)   wob (whole run)
    // [2,10)  xb (f2b->QKV) -> q_ws (norm->attn) -> o_ws (combine->gemm)
    // [10,16) wqkv (f2b->QKV); [10,18) k_ws (norm->attn)
    // [18,26) q_raw, [26,34) k_raw (QKV->norm)
    // [18,50) Opc[4] bf16 slabs (attn->combine)
    // [50,58) vt_ws (QKV epilogue -> attn)
    // [58,59) lpc[4] fp32
    bf16*  wob   = (bf16*)(ws + 0);
    bf16*  xb    = (bf16*)(ws + 2 * MB);
    bf16*  q_ws  = (bf16*)(ws + 2 * MB);
    bf16*  o_ws  = (bf16*)(ws + 2 * MB);
    bf16*  wqkv  = (bf16*)(ws + 10 * MB);
    bf16*  k_ws  = (bf16*)(ws + 10 * MB);
    bf16*  q_raw = (bf16*)(ws + 18 * MB);
    bf16*  k_raw = (bf16*)(ws + 26 * MB);
    bf16*  Opc   = (bf16*)(ws + 18 * MB);
    bf16*  vt_ws = (bf16*)(ws + 50 * MB);
    float* lpc   = (float*)(ws + 58 * MB);

    f2b_all<<<4096, 256, 0, stream>>>(x, wq, wk, wv, wo, xb, wqkv, wob);

    gemm_bt<1><<<dim3(32, 24), 256, 0, stream>>>(xb, wqkv, 4096, 3072, 1024,
                                                 nullptr, q_raw, k_raw, vt_ws);
    norm_rope<<<4096, 256, 0, stream>>>(q_raw, k_raw, cosb, sinb,
                                        qw, kw, q_ws, k_ws);
    attn_kernel<<<2048, 256, 0, stream>>>(q_ws, k_ws, vt_ws, Opc, lpc);
    combine_kernel<<<4096 * 1024 / 8 / 256, 256, 0, stream>>>(Opc, lpc, o_ws);
    gemm_bt<0><<<dim3(32, 8), 256, 0, stream>>>(o_ws, wob, 4096, 1024, 1024,
                                                (float*)d_out, nullptr, nullptr, nullptr);
}

// Round 10
// 149.768 us; speedup vs baseline: 1.8075x; 1.8075x over previous
//
#include <hip/hip_runtime.h>

#define S_LEN 4096
#define DIM   1024
#define NH    16
#define HD    64

typedef __bf16 bf16;
typedef __attribute__((ext_vector_type(8)))  __bf16 bf16x8;
typedef __attribute__((ext_vector_type(4)))  float  f32x4;
typedef __attribute__((ext_vector_type(16))) float  f32x16;
typedef __attribute__((ext_vector_type(4)))  unsigned int uint4v;

typedef __attribute__((address_space(3))) void lds_void;
typedef __attribute__((address_space(1))) void g_void;

#if __has_builtin(__builtin_amdgcn_exp2f)
#define EXP2(x) __builtin_amdgcn_exp2f(x)
#else
#define EXP2(x) exp2f(x)
#endif

// async global->LDS, 16B per lane. LDS dest = wave-uniform base + lane*16.
__device__ __forceinline__ void gl_lds16(const void* g, void* l) {
    __builtin_amdgcn_global_load_lds((g_void*)(void*)g, (lds_void*)l, 16, 0, 0);
}

// pack 2 floats -> 2 bf16 in a dword (v_cvt_pk_bf16_f32)
__device__ __forceinline__ unsigned int pk2(float a, float b) {
    unsigned short ua = __builtin_bit_cast(unsigned short, (bf16)a);
    unsigned short ub = __builtin_bit_cast(unsigned short, (bf16)b);
    return (unsigned int)ua | ((unsigned int)ub << 16);
}

// key-axis permutation for V^T: swap bits 2<->3 (involution, closed within
// each 16-slot MFMA group). Makes PV's A-fragment lane-local (no shuffles).
__device__ __forceinline__ int ksw23(int x) {
    return (x & ~12) | ((x & 8) >> 1) | ((x & 4) << 1);
}

// ---------------- fused fp32 -> bf16 conversions (1 launch, G13) ----------
__global__ __launch_bounds__(256) void f2b_all(
    const float* __restrict__ x,  const float* __restrict__ wq,
    const float* __restrict__ wk, const float* __restrict__ wv,
    const float* __restrict__ wo,
    bf16* __restrict__ xb, bf16* __restrict__ wqkv, bf16* __restrict__ wob)
{
    int b = blockIdx.x;
    const float* src; bf16* dst; int base;
    if (b < 2048)      { src = x;  dst = xb;              base = b; }
    else if (b < 2560) { src = wq; dst = wqkv;            base = b - 2048; }
    else if (b < 3072) { src = wk; dst = wqkv + 1048576;  base = b - 2560; }
    else if (b < 3584) { src = wv; dst = wqkv + 2097152;  base = b - 3072; }
    else               { src = wo; dst = wob;             base = b - 3584; }
    int i = base * 2048 + threadIdx.x * 8;
    float4 a = *(const float4*)(src + i);
    float4 c = *(const float4*)(src + i + 4);
    bf16x8 r;
    r[0]=(bf16)a.x; r[1]=(bf16)a.y; r[2]=(bf16)a.z; r[3]=(bf16)a.w;
    r[4]=(bf16)c.x; r[5]=(bf16)c.y; r[6]=(bf16)c.z; r[7]=(bf16)c.w;
    *(bf16x8*)(dst + i) = r;
}

// ---------------- m97-style GEMM: C = A * B^T (A[M][K], B[N][K]) ----------
// MODE 0: fp32 out [M][N].
// MODE 1: QKV: cols [0,1024)->outQ[s][c], [1024,2048)->outK[s][c] (bf16);
//   [2048,3072)->V^T directly: outV = vt[H][64][S_LEN], stored with the
//   per-64-key-tile bit2<->3 permutation and (d&7)<<3 XOR pre-swizzle.
template <int MODE>
__global__ __launch_bounds__(256) void gemm_bt(
    const bf16* __restrict__ A, const bf16* __restrict__ B,
    int M, int N, int K,
    float* __restrict__ outF,
    bf16* __restrict__ outQ, bf16* __restrict__ outK, bf16* __restrict__ outV)
{
    __shared__ bf16 As[128][32];
    __shared__ bf16 Bs[128][32];
    const int bm = blockIdx.x, bn = blockIdx.y;
    const int tid  = threadIdx.x;
    const int wave = tid >> 6, lane = tid & 63;
    const int g = lane >> 4, r = lane & 15;
    const int wr = wave >> 1, wc = wave & 1;
    const int rr = lane >> 2, cc = (lane & 3) * 8;

    f32x4 acc[4][4] = {};

    const bf16* Ab = A + (size_t)(bm * 128) * K;
    const bf16* Bb = B + (size_t)(bn * 128) * K;

    for (int k0 = 0; k0 < K; k0 += 32) {
        #pragma unroll
        for (int i = 0; i < 2; ++i) {
            gl_lds16(Ab + (size_t)(wave*32 + i*16 + rr) * K + k0 + cc, &As[wave*32 + i*16][0]);
            gl_lds16(Bb + (size_t)(wave*32 + i*16 + rr) * K + k0 + cc, &Bs[wave*32 + i*16][0]);
        }
        __syncthreads();
        bf16x8 a[4], b[4];
        #pragma unroll
        for (int m = 0; m < 4; ++m) a[m] = *(const bf16x8*)&As[wr*64 + m*16 + r][g*8];
        #pragma unroll
        for (int n = 0; n < 4; ++n) b[n] = *(const bf16x8*)&Bs[wc*64 + n*16 + r][g*8];
        #pragma unroll
        for (int m = 0; m < 4; ++m)
            #pragma unroll
            for (int n = 0; n < 4; ++n)
                acc[m][n] = __builtin_amdgcn_mfma_f32_16x16x32_bf16(a[m], b[n], acc[m][n], 0, 0, 0);
        __syncthreads();
    }

    #pragma unroll
    for (int m = 0; m < 4; ++m)
        #pragma unroll
        for (int n = 0; n < 4; ++n)
            #pragma unroll
            for (int i = 0; i < 4; ++i) {
                int row = bm*128 + wr*64 + m*16 + g*4 + i;
                int col = bn*128 + wc*64 + n*16 + r;
                float val = acc[m][n][i];
                if (MODE == 0) {
                    outF[(size_t)row * N + col] = val;
                } else {
                    if (col < 1024)       outQ[(size_t)row * 1024 + col]          = (bf16)val;
                    else if (col < 2048)  outK[(size_t)row * 1024 + (col - 1024)] = (bf16)val;
                    else {
                        int c = col - 2048;
                        int hh = c >> 6, d = c & 63;
                        int pos = ksw23(row & 63) ^ ((d & 7) << 3);
                        outV[((size_t)(hh * HD + d)) * S_LEN + (row & ~63) + pos] = (bf16)val;
                    }
                }
            }
}

// ---------------- per-head RMSNorm + RoPE, [S][1024] -> [H][S][64] --------
// 8 rows per wave, bf16x8 vectorized (G13). Group reduce: shfl_xor 1,2,4.
// RoPE partner (d +/- 32) = shfl_xor(.,4). K pre-swizzled: d ^ ((s&7)<<3).
__global__ __launch_bounds__(256) void norm_rope(
    const bf16* __restrict__ qr, const bf16* __restrict__ kr,
    const float* __restrict__ cosb, const float* __restrict__ sinb,
    const float* __restrict__ qw, const float* __restrict__ kw,
    bf16* __restrict__ qo, bf16* __restrict__ ko)
{
    int wgl  = blockIdx.x * 4 + (threadIdx.x >> 6);   // [0, 16384)
    int lane = threadIdx.x & 63;
    int isK  = wgl >= 8192;
    int w2   = wgl & 8191;
    int s    = w2 >> 1;
    int h    = ((w2 & 1) << 3) + (lane >> 3);
    int d0   = (lane & 7) << 3;
    const bf16*  src = isK ? kr : qr;
    const float* w   = isK ? kw : qw;

    bf16x8 xv = *(const bf16x8*)(src + (size_t)s * DIM + h * HD + d0);
    float x[8];
    #pragma unroll
    for (int e = 0; e < 8; ++e) x[e] = (float)xv[e];
    float ss = 0.f;
    #pragma unroll
    for (int e = 0; e < 8; ++e) ss += x[e] * x[e];
    ss += __shfl_xor(ss, 1);
    ss += __shfl_xor(ss, 2);
    ss += __shfl_xor(ss, 4);
    float rn = rsqrtf(ss * (1.0f / 64.0f) + 1e-6f);

    float4 w0 = *(const float4*)(w + d0);
    float4 w1 = *(const float4*)(w + d0 + 4);
    float wv[8] = {w0.x, w0.y, w0.z, w0.w, w1.x, w1.y, w1.z, w1.w};
    float xn[8], pr[8];
    #pragma unroll
    for (int e = 0; e < 8; ++e) xn[e] = x[e] * rn * wv[e];
    #pragma unroll
    for (int e = 0; e < 8; ++e) pr[e] = __shfl_xor(xn[e], 4);

    int dm = d0 & 31;
    float4 c0 = *(const float4*)(cosb + s * 32 + dm);
    float4 c1 = *(const float4*)(cosb + s * 32 + dm + 4);
    float4 sn0 = *(const float4*)(sinb + s * 32 + dm);
    float4 sn1 = *(const float4*)(sinb + s * 32 + dm + 4);
    float cv[8] = {c0.x, c0.y, c0.z, c0.w, c1.x, c1.y, c1.z, c1.w};
    float sv[8] = {sn0.x, sn0.y, sn0.z, sn0.w, sn1.x, sn1.y, sn1.z, sn1.w};

    const bool lo = (d0 < 32);
    bf16x8 y;
    #pragma unroll
    for (int e = 0; e < 8; ++e) {
        float t = lo ? (xn[e] * cv[e] - pr[e] * sv[e])
                     : (xn[e] * cv[e] + pr[e] * sv[e]);
        y[e] = (bf16)t;
    }
    size_t ob = ((size_t)h * S_LEN + s) * HD;
    if (isK) *(bf16x8*)(ko + ob + (d0 ^ ((s & 7) << 3))) = y;
    else     *(bf16x8*)(qo + ob + d0)                    = y;
}

// ---------------- causal flash attention, 32x32 MFMA, 4-chunk split -------
// 2048 blocks = queue at 4/CU (256 thr, 4 waves -- proven round-8 body).
// idx: h = idx&15; u = idx>>4: qt = 31-(u>>2) (LPT order), c = u&3;
// tiles t in [c*nt/4, (c+1)*nt/4), nt = 2qt+2. Static-max softmax (diag
// score = +8 exactly): P = exp2(S*C1 - C2) -- pure sums, chunk partials
// (bf16 O slabs + fp32 l) combine by addition.
// Swapped QK^T: lane q = lane&31 owns its q-row's P at
// k = kn*32 + (rg&3) + 8*(rg>>2) + 4*hi (verified 32x32 C/D layout).
// V^T pre-permuted (ksw23) + XOR-swizzled -> PV A-fragment is lane-local.
// Unroll-2 via MACRO (r9 post-mortem: a thrice-called fat lambda was NOT
// inlined -> by-ref captures went to stack -> 450MB scratch traffic; the
// macro guarantees textual inlining with literal buffer indices).
__global__ __launch_bounds__(256, 4) void attn_kernel(
    const bf16* __restrict__ q, const bf16* __restrict__ k,
    const bf16* __restrict__ vt,
    bf16* __restrict__ Opc, float* __restrict__ lpc)
{
    __shared__ bf16 Ks[2][64][64];   // [keys][d], rows pre-swizzled
    __shared__ bf16 Vt[2][64][64];   // [d][keys], permuted+pre-swizzled

    const int idx = blockIdx.x;
    const int h = idx & 15;
    const int u = idx >> 4;
    const int qt = 31 - (u >> 2);
    const int c  = u & 3;
    const int nt = 2 * qt + 2;
    const int t0 = (c * nt) >> 2;
    const int t1 = ((c + 1) * nt) >> 2;

    const int q0 = qt * 128;
    const int tid = threadIdx.x;
    const int wave = tid >> 6, lane = tid & 63;
    const int l31 = lane & 31, hi = lane >> 5;

    const bf16* qh  = q  + (size_t)h * S_LEN * HD;
    const bf16* kh  = k  + (size_t)h * S_LEN * HD;
    const bf16* vth = vt + (size_t)h * HD * S_LEN;

    // Q B-fragments: lane holds its q-row (q0+wave*32+l31), 8 d-elems per step
    const int qrow = q0 + wave * 32 + l31;
    bf16x8 qf[4];
    #pragma unroll
    for (int ds4 = 0; ds4 < 4; ++ds4)
        qf[ds4] = *(const bf16x8*)(qh + (size_t)qrow * HD + ds4 * 16 + hi * 8);

    float l_run = 0.f;
    f32x16 acc_o[2] = {};

    const int srow = lane >> 3, scol = (lane & 7) * 8;
    const float C1 = 0.125f * 1.44269504088896f;   // scale * log2(e)
    const float C2 = 8.0f * 1.44269504088896f;     // static max * log2(e)

    auto stage = [&](int t, int buf) {
        const int k0 = t * 64;
        const bf16* kb = kh + (size_t)(k0 + wave * 16) * HD;
        gl_lds16(kb + (size_t)(srow    ) * HD + scol, &Ks[buf][wave * 16][0]);
        gl_lds16(kb + (size_t)(srow + 8) * HD + scol, &Ks[buf][wave * 16 + 8][0]);
        const bf16* vb = vth + (size_t)(wave * 16) * S_LEN + k0;
        gl_lds16(vb + (size_t)(srow    ) * S_LEN + scol, &Vt[buf][wave * 16][0]);
        gl_lds16(vb + (size_t)(srow + 8) * S_LEN + scol, &Vt[buf][wave * 16 + 8][0]);
    };

// textually-inlined tile compute; BUF is a literal so every LDS fragment
// address is loop-invariant (hoisted once), no runtime buffer selects.
#define COMPUTE_TILE(T, BUF)                                                  \
    do {                                                                      \
        const int k0_ = (T) * 64;                                             \
        const bool masked_ = ((T) >= 2 * qt);                                 \
        f32x16 sacc_[2];                                                      \
        __builtin_amdgcn_s_setprio(1);                                        \
        _Pragma("unroll")                                                     \
        for (int kn = 0; kn < 2; ++kn) {                                      \
            const int krow = kn * 32 + l31;                                   \
            const int sw = (krow & 7) << 3;                                   \
            f32x16 z = {};                                                    \
            _Pragma("unroll")                                                 \
            for (int ds4 = 0; ds4 < 4; ++ds4) {                               \
                bf16x8 kfr = *(const bf16x8*)&Ks[BUF][krow][(ds4 * 16 + hi * 8) ^ sw]; \
                z = __builtin_amdgcn_mfma_f32_32x32x16_bf16(kfr, qf[ds4], z, 0, 0, 0); \
            }                                                                 \
            sacc_[kn] = z;                                                    \
        }                                                                     \
        __builtin_amdgcn_s_setprio(0);                                        \
        float p_[32];                                                         \
        _Pragma("unroll")                                                     \
        for (int kn = 0; kn < 2; ++kn)                                        \
            _Pragma("unroll")                                                 \
            for (int rg = 0; rg < 16; ++rg) {                                 \
                float e = EXP2(fmaf(sacc_[kn][rg], C1, -C2));                 \
                if (masked_) {                                                \
                    int kloc = kn * 32 + (rg & 3) + 8 * (rg >> 2) + 4 * hi;   \
                    if (k0_ + kloc > qrow) e = 0.f;                           \
                }                                                             \
                p_[kn * 16 + rg] = e;                                         \
            }                                                                 \
        float s0_ = 0.f, s1_ = 0.f, s2_ = 0.f, s3_ = 0.f;                     \
        _Pragma("unroll")                                                     \
        for (int j = 0; j < 8; ++j) {                                         \
            s0_ += p_[4*j];   s1_ += p_[4*j+1];                               \
            s2_ += p_[4*j+2]; s3_ += p_[4*j+3];                               \
        }                                                                     \
        float rs_ = (s0_ + s1_) + (s2_ + s3_);                                \
        rs_ += __shfl_xor(rs_, 32);                                           \
        l_run += rs_;                                                         \
        bf16x8 pa_[4];                                                        \
        _Pragma("unroll")                                                     \
        for (int ks4 = 0; ks4 < 4; ++ks4) {                                   \
            uint4v w_;                                                        \
            w_.x = pk2(p_[8*ks4+0], p_[8*ks4+1]);                             \
            w_.y = pk2(p_[8*ks4+2], p_[8*ks4+3]);                             \
            w_.z = pk2(p_[8*ks4+4], p_[8*ks4+5]);                             \
            w_.w = pk2(p_[8*ks4+6], p_[8*ks4+7]);                             \
            pa_[ks4] = __builtin_bit_cast(bf16x8, w_);                        \
        }                                                                     \
        __builtin_amdgcn_s_setprio(1);                                        \
        _Pragma("unroll")                                                     \
        for (int n = 0; n < 2; ++n) {                                         \
            const int d = n * 32 + l31;                                       \
            const int sw = (d & 7) << 3;                                      \
            f32x16 a = acc_o[n];                                              \
            _Pragma("unroll")                                                 \
            for (int ks4 = 0; ks4 < 4; ++ks4) {                               \
                bf16x8 vfr = *(const bf16x8*)&Vt[BUF][d][(ks4 * 16 + hi * 8) ^ sw]; \
                a = __builtin_amdgcn_mfma_f32_32x32x16_bf16(pa_[ks4], vfr, a, 0, 0, 0); \
            }                                                                 \
            acc_o[n] = a;                                                     \
        }                                                                     \
        __builtin_amdgcn_s_setprio(0);                                        \
    } while (0)

    if (t0 < t1) {
        stage(t0, 0);
        asm volatile("s_waitcnt vmcnt(0)" ::: "memory");
        __syncthreads();
        int t = t0;
        while (t + 2 <= t1) {
            stage(t + 1, 1);
            COMPUTE_TILE(t, 0);
            asm volatile("s_waitcnt vmcnt(0)" ::: "memory");
            __syncthreads();
            if (t + 2 < t1) stage(t + 2, 0);
            COMPUTE_TILE(t + 1, 1);
            asm volatile("s_waitcnt vmcnt(0)" ::: "memory");
            __syncthreads();
            t += 2;
        }
        if (t < t1) COMPUTE_TILE(t, 0);   // odd tail (already staged in buf0)
    }
#undef COMPUTE_TILE

    // partial epilogue: bf16 O slab for this chunk + fp32 l. C/D: col = l31,
    // row q = (rg&3) + 8*(rg>>2) + 4*hi. Empty chunks write zeros.
    bf16* Op = Opc + (size_t)c * S_LEN * DIM;
    #pragma unroll
    for (int n = 0; n < 2; ++n)
        #pragma unroll
        for (int rg = 0; rg < 16; ++rg) {
            int s_abs = q0 + wave * 32 + (rg & 3) + 8 * (rg >> 2) + 4 * hi;
            Op[(size_t)s_abs * DIM + h * HD + n * 32 + l31] = (bf16)acc_o[n][rg];
        }
    if (lane < 32)
        lpc[c * (NH * S_LEN) + h * S_LEN + (q0 + wave * 32 + lane)] = l_run;
}

// ---------------- combine 4 chunk partials + normalize -> bf16 ------------
__global__ __launch_bounds__(256) void combine_kernel(
    const bf16* __restrict__ Opc, const float* __restrict__ lpc,
    bf16* __restrict__ o)
{
    int gid = blockIdx.x * 256 + threadIdx.x;
    int e = gid * 8;
    int s = e >> 10, h = (e & 1023) >> 6;
    float a[8] = {};
    #pragma unroll
    for (int c = 0; c < 4; ++c) {
        bf16x8 v = *(const bf16x8*)(Opc + (size_t)c * S_LEN * DIM + e);
        #pragma unroll
        for (int j = 0; j < 8; ++j) a[j] += (float)v[j];
    }
    float l = 0.f;
    #pragma unroll
    for (int c = 0; c < 4; ++c) l += lpc[c * (NH * S_LEN) + h * S_LEN + s];
    float inv = __builtin_amdgcn_rcpf(l);
    bf16x8 rv;
    #pragma unroll
    for (int j = 0; j < 8; ++j) rv[j] = (bf16)(a[j] * inv);
    *(bf16x8*)(o + e) = rv;
}

// ---------------------------------------------------------------------------
extern "C" void kernel_launch(void* const* d_in, const int* in_sizes, int n_in,
                              void* d_out, int out_size, void* d_ws, size_t ws_size,
                              hipStream_t stream)
{
    const float* x    = (const float*)d_in[0];
    const float* cosb = (const float*)d_in[1];
    const float* sinb = (const float*)d_in[2];
    const float* wq   = (const float*)d_in[4];
    const float* wk   = (const float*)d_in[5];
    const float* wv   = (const float*)d_in[6];
    const float* wo   = (const float*)d_in[7];
    const float* qw   = (const float*)d_in[8];
    const float* kw   = (const float*)d_in[9];

    char* ws = (char*)d_ws;
    const size_t MB = 1024 * 1024;
    // region map (MB), temporal reuse:
    // [0,2)   wob (whole run)
    // [2,10)  xb (f2b->QKV) -> q_ws (norm->attn) -> o_ws (combine->gemm)
    // [10,16) wqkv (f2b->QKV); [10,18) k_ws (norm->attn)
    // [18,26) q_raw, [26,34) k_raw (QKV->norm)
    // [18,50) Opc[4] bf16 slabs (attn->combine)
    // [50,58) vt_ws (QKV epilogue -> attn)
    // [58,59) lpc[4] fp32
    bf16*  wob   = (bf16*)(ws + 0);
    bf16*  xb    = (bf16*)(ws + 2 * MB);
    bf16*  q_ws  = (bf16*)(ws + 2 * MB);
    bf16*  o_ws  = (bf16*)(ws + 2 * MB);
    bf16*  wqkv  = (bf16*)(ws + 10 * MB);
    bf16*  k_ws  = (bf16*)(ws + 10 * MB);
    bf16*  q_raw = (bf16*)(ws + 18 * MB);
    bf16*  k_raw = (bf16*)(ws + 26 * MB);
    bf16*  Opc   = (bf16*)(ws + 18 * MB);
    bf16*  vt_ws = (bf16*)(ws + 50 * MB);
    float* lpc   = (float*)(ws + 58 * MB);

    f2b_all<<<4096, 256, 0, stream>>>(x, wq, wk, wv, wo, xb, wqkv, wob);

    gemm_bt<1><<<dim3(32, 24), 256, 0, stream>>>(xb, wqkv, 4096, 3072, 1024,
                                                 nullptr, q_raw, k_raw, vt_ws);
    norm_rope<<<4096, 256, 0, stream>>>(q_raw, k_raw, cosb, sinb,
                                        qw, kw, q_ws, k_ws);
    attn_kernel<<<2048, 256, 0, stream>>>(q_ws, k_ws, vt_ws, Opc, lpc);
    combine_kernel<<<4096 * 1024 / 8 / 256, 256, 0, stream>>>(Opc, lpc, o_ws);
    gemm_bt<0><<<dim3(32, 8), 256, 0, stream>>>(o_ws, wob, 4096, 1024, 1024,
                                                (float*)d_out, nullptr, nullptr, nullptr);
}